// Round 9
// baseline (201.334 us; speedup 1.0000x reference)
//
#include <hip/hip_runtime.h>
#include <hip/hip_bf16.h>

// ---------------------------------------------------------------------------
// AttentionHead B=4,S=2048,D=1024 — all-f16 pipeline, round 9.
// gemm3b (new): 256x128 BK=64 TRIPLE-buffered (144 KiB LDS), stage tile t+2
//   during tile t, boundary vmcnt(6) -> issue-to-wait distance = 2 K-tiles
//   (~620+ cyc) covers HBM/L3 latency. For proj (768 blocks) + PV (256).
// gemm8p (r7): 256x256 BK=64 4-phase — scores (256 blocks).
// R8 lesson: 2-phase dbuf's 1-phase staging distance exposed ~700 cyc of
// latency per K-tile at every boundary (MfmaUtil 30%). Depth, not fill.
// ws (MiB): XF@0(48) WT@48(6) PROJ@54(48) VT@102(16) SC@118(32,f16)
//           P@0(32,f16, alias XF). high-water 150 MiB.
// ---------------------------------------------------------------------------

typedef __attribute__((ext_vector_type(4))) float    f32x4;
typedef __attribute__((ext_vector_type(8))) _Float16 f16x8;
typedef __attribute__((ext_vector_type(4))) _Float16 f16x4;

constexpr size_t MiB = 1u << 20;
constexpr size_t MK  = (size_t)8192 * 1024;
constexpr size_t WSZ = (size_t)1024 * 1024;

__device__ __forceinline__ void gload_lds16(const void* g, void* l) {
  __builtin_amdgcn_global_load_lds(
      (const __attribute__((address_space(1))) unsigned int*)g,
      (__attribute__((address_space(3))) unsigned int*)l, 16, 0, 0);
}

#define MFMA16(a, b, c) __builtin_amdgcn_mfma_f32_16x16x32_f16(a, b, c, 0, 0, 0)

// XCD-chunked bijective block swizzle (requires total blocks % 8 == 0).
__device__ __forceinline__ void swz_block(int& bx, int& by, int& bz) {
  unsigned gx = gridDim.x, gy = gridDim.y;
  unsigned flat = blockIdx.x + gx * (blockIdx.y + gy * blockIdx.z);
  unsigned total = gx * gy * gridDim.z;
  unsigned cpx = total >> 3;
  unsigned s = (flat & 7) * cpx + (flat >> 3);
  bx = s % gx; s /= gx; by = s % gy; bz = s / gy;
}

// ---------------------------------------------------------------------------
__global__ __launch_bounds__(256) void convert_x(
    const float* __restrict__ x0, const float* __restrict__ x1,
    const float* __restrict__ x2, _Float16* __restrict__ XF)
{
  const int z = blockIdx.z;
  const float* x = z == 0 ? x0 : (z == 1 ? x1 : x2);
  size_t i = ((size_t)blockIdx.x * 256 + threadIdx.x) * 4;
  float4 v = *(const float4*)(x + i);
  f16x4 h = {(_Float16)v.x, (_Float16)v.y, (_Float16)v.z, (_Float16)v.w};
  *(f16x4*)(XF + (size_t)z * MK + i) = h;
}

// ---------------------------------------------------------------------------
__global__ __launch_bounds__(256) void transpose_conv_w(
    const float* __restrict__ w0, const float* __restrict__ w1,
    const float* __restrict__ w2, _Float16* __restrict__ WT)
{
  const int z = blockIdx.z;
  const float* W = z == 0 ? w0 : (z == 1 ? w1 : w2);
  _Float16* o = WT + (size_t)z * WSZ;
  __shared__ float tile[32][33];
  const int bx = blockIdx.x * 32;
  const int by = blockIdx.y * 32;
  const int tx = threadIdx.x & 31, ty = threadIdx.x >> 5;
  #pragma unroll
  for (int r = 0; r < 32; r += 8)
    tile[ty + r][tx] = W[(size_t)(by + ty + r) * 1024 + bx + tx];
  __syncthreads();
  #pragma unroll
  for (int r = 0; r < 32; r += 8)
    o[(size_t)(bx + ty + r) * 1024 + by + tx] = (_Float16)tile[tx][ty + r];
}

// ---------------------------------------------------------------------------
__global__ __launch_bounds__(256) void transpose_v(
    const _Float16* __restrict__ V, _Float16* __restrict__ Vt)
{
  const _Float16* v = V + (size_t)blockIdx.z * 2048 * 1024;
  _Float16* o = Vt + (size_t)blockIdx.z * 1024 * 2048;
  __shared__ _Float16 tile[32][33];
  const int bx = blockIdx.x * 32;   // e
  const int by = blockIdx.y * 32;   // s
  const int tx = threadIdx.x & 31, ty = threadIdx.x >> 5;
  #pragma unroll
  for (int r = 0; r < 32; r += 8)
    tile[ty + r][tx] = v[(size_t)(by + ty + r) * 1024 + bx + tx];
  __syncthreads();
  #pragma unroll
  for (int r = 0; r < 32; r += 8)
    o[(size_t)(bx + ty + r) * 2048 + by + tx] = tile[tx][ty + r];
}

// ---------------------------------------------------------------------------
// gemm8p (r7, unchanged): 256x256 BK=64, 4 phases/K-tile. For scores.
// MODE 0: f32*scale ; 1: f16 ; 2: f16*scale.
template <int MODE>
__global__ __launch_bounds__(512, 2) void gemm8p(
    const _Float16* __restrict__ At, size_t sA,
    const _Float16* __restrict__ Bt, size_t sB,
    void* __restrict__ Cv, size_t sCz,
    int N, int K, float scale)
{
  extern __shared__ char lds[];
  int bx, by, bz;
  swz_block(bx, by, bz);
  const _Float16* A = At + (size_t)bz * sA;
  const _Float16* B = Bt + (size_t)bz * sB;

  const int gm0 = by * 256, gn0 = bx * 256;
  const int tid = threadIdx.x;
  const int lane = tid & 63, wave = tid >> 6;
  const int wm = (wave >> 2) * 128;
  const int wn = (wave & 3) * 64;
  const int fr = lane & 15, fq = lane >> 4;
  const int nkt = K >> 6;

  const int clog = ((tid & 7) ^ ((tid >> 3) & 7)) * 8;
  const _Float16* srcA = A + (size_t)(gm0 + (tid >> 3)) * K + clog;
  const _Float16* srcB = B + (size_t)(gn0 + (tid >> 3)) * K + clog;
  char* const dst0 = lds + tid * 16;

  auto SH = [&](int tile, int h) {
    const _Float16* s = (h < 2 ? srcA : srcB) + (size_t)((h & 1) * 128) * K
                        + tile * 64;
    char* d = dst0 + (tile & 1) * 65536 + h * 16384;
    gload_lds16(s, d);
    gload_lds16(s + (size_t)64 * K, d + 8192);
  };

  const int axor = fr & 7;
  const int pc0 = (fq ^ axor) * 16;
  const int pc1 = ((4 + fq) ^ axor) * 16;
  const int arb = (wm + fr) * 128;
  const int brb = 32768 + (wn + fr) * 128;

  f32x4 acc[8][4] = {};
  f16x8 af[4][2], b0[2][2], b1[2][2];

  SH(0, 0); SH(0, 1); SH(0, 2); SH(0, 3);
  if (nkt > 1) {
    SH(1, 0);
    asm volatile("s_waitcnt vmcnt(2)" ::: "memory");
  } else {
    asm volatile("s_waitcnt vmcnt(0)" ::: "memory");
  }
  __builtin_amdgcn_s_barrier();
  __builtin_amdgcn_sched_barrier(0);

#define PHASE_MID                                          \
  __builtin_amdgcn_s_barrier();                            \
  asm volatile("s_waitcnt lgkmcnt(0)" ::: "memory");       \
  __builtin_amdgcn_sched_barrier(0);                       \
  __builtin_amdgcn_s_setprio(1);
#define PHASE_END                                          \
  __builtin_amdgcn_s_setprio(0);                           \
  __builtin_amdgcn_sched_barrier(0);                       \
  __builtin_amdgcn_s_barrier();

  for (int t = 0; t < nkt; ++t) {
    const char* buf = lds + (t & 1) * 65536;
    const bool st1 = (t + 1) < nkt;

    #pragma unroll
    for (int mi = 0; mi < 4; ++mi) {
      af[mi][0] = *(const f16x8*)(buf + arb + mi * 2048 + pc0);
      af[mi][1] = *(const f16x8*)(buf + arb + mi * 2048 + pc1);
    }
    #pragma unroll
    for (int ni = 0; ni < 2; ++ni) {
      b0[ni][0] = *(const f16x8*)(buf + brb + ni * 2048 + pc0);
      b0[ni][1] = *(const f16x8*)(buf + brb + ni * 2048 + pc1);
    }
    if (st1) SH(t + 1, 1);
    PHASE_MID
    #pragma unroll
    for (int mi = 0; mi < 4; ++mi)
      #pragma unroll
      for (int ni = 0; ni < 2; ++ni)
        #pragma unroll
        for (int kk = 0; kk < 2; ++kk)
          acc[mi][ni] = MFMA16(af[mi][kk], b0[ni][kk], acc[mi][ni]);
    PHASE_END

    #pragma unroll
    for (int ni = 0; ni < 2; ++ni) {
      b1[ni][0] = *(const f16x8*)(buf + brb + (ni + 2) * 2048 + pc0);
      b1[ni][1] = *(const f16x8*)(buf + brb + (ni + 2) * 2048 + pc1);
    }
    if (st1) SH(t + 1, 2);
    PHASE_MID
    #pragma unroll
    for (int mi = 0; mi < 4; ++mi)
      #pragma unroll
      for (int ni = 0; ni < 2; ++ni)
        #pragma unroll
        for (int kk = 0; kk < 2; ++kk)
          acc[mi][ni + 2] = MFMA16(af[mi][kk], b1[ni][kk], acc[mi][ni + 2]);
    PHASE_END

    #pragma unroll
    for (int mi = 0; mi < 4; ++mi) {
      af[mi][0] = *(const f16x8*)(buf + arb + (mi + 4) * 2048 + pc0);
      af[mi][1] = *(const f16x8*)(buf + arb + (mi + 4) * 2048 + pc1);
    }
    if (st1) SH(t + 1, 3);
    PHASE_MID
    #pragma unroll
    for (int mi = 0; mi < 4; ++mi)
      #pragma unroll
      for (int ni = 0; ni < 2; ++ni)
        #pragma unroll
        for (int kk = 0; kk < 2; ++kk)
          acc[mi + 4][ni] = MFMA16(af[mi][kk], b0[ni][kk], acc[mi + 4][ni]);
    PHASE_END

    const bool st2 = (t + 2) < nkt;
    if (st2) SH(t + 2, 0);
    __builtin_amdgcn_s_barrier();
    __builtin_amdgcn_s_setprio(1);
    #pragma unroll
    for (int mi = 0; mi < 4; ++mi)
      #pragma unroll
      for (int ni = 0; ni < 2; ++ni)
        #pragma unroll
        for (int kk = 0; kk < 2; ++kk)
          acc[mi + 4][ni + 2] = MFMA16(af[mi][kk], b1[ni][kk], acc[mi + 4][ni + 2]);
    __builtin_amdgcn_s_setprio(0);
    __builtin_amdgcn_sched_barrier(0);
    if (st2) asm volatile("s_waitcnt vmcnt(2)" ::: "memory");
    else     asm volatile("s_waitcnt vmcnt(0)" ::: "memory");
    __builtin_amdgcn_s_barrier();
  }
#undef PHASE_MID
#undef PHASE_END

  const int erow = gm0 + wm + fq * 4;
  const int ecol = gn0 + wn + fr;
  #pragma unroll
  for (int m = 0; m < 8; ++m)
    #pragma unroll
    for (int n = 0; n < 4; ++n) {
      size_t base = (size_t)(erow + m * 16) * N + (ecol + n * 16);
      #pragma unroll
      for (int r = 0; r < 4; ++r) {
        float v = acc[m][n][r];
        if constexpr (MODE == 0)
          ((float*)Cv + (size_t)bz * sCz)[base + (size_t)r * N] = v * scale;
        else if constexpr (MODE == 1)
          ((_Float16*)Cv + (size_t)bz * sCz)[base + (size_t)r * N] = (_Float16)v;
        else
          ((_Float16*)Cv + (size_t)bz * sCz)[base + (size_t)r * N] =
              (_Float16)(v * scale);
      }
    }
}

// ---------------------------------------------------------------------------
// gemm3b (new): 256(M)x128(N), BK=64, 512 thr = 8 waves (4M x 2N, wave 64x64).
// TRIPLE-buffered LDS (3 x 48 KiB): A [256][64] @0, B [128][64] @32768 per buf.
// Staging unit = 8 KiB (1 gload/thread); 6 units/tile (A:4, B:2).
// Tile t stages units 0-2 of t+2 in P0, units 3-5 in P1.
// Boundary vmcnt(6): tile t+1 landed, t+2's 6 loads in flight.
// Issue-to-wait distance = 2 K-tiles (~620+ cyc MFMA) >= HBM/L3 latency.
// MODE 0: f32*scale ; 1: f16.
template <int MODE>
__global__ __launch_bounds__(512, 2) void gemm3b(
    const _Float16* __restrict__ At, size_t sA,
    const _Float16* __restrict__ Bt, size_t sB,
    void* __restrict__ Cv, size_t sCz,
    int N, int K, float scale)
{
  extern __shared__ char lds[];
  int bx, by, bz;
  swz_block(bx, by, bz);
  const _Float16* A = At + (size_t)bz * sA;
  const _Float16* B = Bt + (size_t)bz * sB;

  const int gm0 = by * 256, gn0 = bx * 128;
  const int tid = threadIdx.x;
  const int lane = tid & 63, wave = tid >> 6;
  const int wm = (wave >> 1) * 64;    // 4 M groups of 64
  const int wn = (wave & 1) * 64;     // 2 N groups of 64
  const int fr = lane & 15, fq = lane >> 4;
  const int nkt = K >> 6;

  const int clog = ((tid & 7) ^ ((tid >> 3) & 7)) * 8;
  const _Float16* srcA = A + (size_t)(gm0 + (tid >> 3)) * K + clog;
  const _Float16* srcB = B + (size_t)(gn0 + (tid >> 3)) * K + clog;
  char* const dst0 = lds + tid * 16;

  // unit u: 0..3 = A rows u*64..u*64+63 ; 4..5 = B rows (u-4)*64.. (8KiB each)
  auto SHU = [&](int tile, int u) {
    const _Float16* s = (u < 4 ? srcA + (size_t)(u * 64) * K
                               : srcB + (size_t)((u - 4) * 64) * K)
                        + tile * 64;
    gload_lds16(s, dst0 + (tile % 3) * 49152 + u * 8192);
  };

  const int axor = fr & 7;
  const int pc0 = (fq ^ axor) * 16;
  const int pc1 = ((4 + fq) ^ axor) * 16;
  const int arb = (wm + fr) * 128;
  const int brb = 32768 + (wn + fr) * 128;

  f32x4 acc[4][4] = {};
  f16x8 af[4][2], b0[2][2], b1[2][2];

  // prologue: tiles 0 and 1 fully (12 loads); wait tile 0 (vmcnt 6)
  #pragma unroll
  for (int u = 0; u < 6; ++u) SHU(0, u);
  if (nkt > 1) {
    #pragma unroll
    for (int u = 0; u < 6; ++u) SHU(1, u);
    asm volatile("s_waitcnt vmcnt(6)" ::: "memory");
  } else {
    asm volatile("s_waitcnt vmcnt(0)" ::: "memory");
  }
  __builtin_amdgcn_s_barrier();
  __builtin_amdgcn_sched_barrier(0);

  for (int t = 0; t < nkt; ++t) {
    const char* buf = lds + (t % 3) * 49152;
    const bool st2 = (t + 2) < nkt;

    // ---- P0: read af(8) + b0(4); stage units 0-2 of t+2; MFMA m x n0-1
    #pragma unroll
    for (int mi = 0; mi < 4; ++mi) {
      af[mi][0] = *(const f16x8*)(buf + arb + mi * 2048 + pc0);
      af[mi][1] = *(const f16x8*)(buf + arb + mi * 2048 + pc1);
    }
    #pragma unroll
    for (int ni = 0; ni < 2; ++ni) {
      b0[ni][0] = *(const f16x8*)(buf + brb + ni * 2048 + pc0);
      b0[ni][1] = *(const f16x8*)(buf + brb + ni * 2048 + pc1);
    }
    if (st2) { SHU(t + 2, 0); SHU(t + 2, 1); SHU(t + 2, 2); }
    __builtin_amdgcn_s_barrier();
    asm volatile("s_waitcnt lgkmcnt(0)" ::: "memory");
    __builtin_amdgcn_sched_barrier(0);
    __builtin_amdgcn_s_setprio(1);
    #pragma unroll
    for (int mi = 0; mi < 4; ++mi)
      #pragma unroll
      for (int ni = 0; ni < 2; ++ni)
        #pragma unroll
        for (int kk = 0; kk < 2; ++kk)
          acc[mi][ni] = MFMA16(af[mi][kk], b0[ni][kk], acc[mi][ni]);
    __builtin_amdgcn_s_setprio(0);
    __builtin_amdgcn_sched_barrier(0);
    __builtin_amdgcn_s_barrier();

    // ---- P1: read b1(4); stage units 3-5 of t+2; MFMA m x n2-3; vmcnt(6)
    #pragma unroll
    for (int ni = 0; ni < 2; ++ni) {
      b1[ni][0] = *(const f16x8*)(buf + brb + (ni + 2) * 2048 + pc0);
      b1[ni][1] = *(const f16x8*)(buf + brb + (ni + 2) * 2048 + pc1);
    }
    if (st2) { SHU(t + 2, 3); SHU(t + 2, 4); SHU(t + 2, 5); }
    __builtin_amdgcn_s_barrier();
    asm volatile("s_waitcnt lgkmcnt(0)" ::: "memory");
    __builtin_amdgcn_sched_barrier(0);
    __builtin_amdgcn_s_setprio(1);
    #pragma unroll
    for (int mi = 0; mi < 4; ++mi)
      #pragma unroll
      for (int ni = 0; ni < 2; ++ni)
        #pragma unroll
        for (int kk = 0; kk < 2; ++kk)
          acc[mi][ni + 2] = MFMA16(af[mi][kk], b1[ni][kk], acc[mi][ni + 2]);
    __builtin_amdgcn_s_setprio(0);
    __builtin_amdgcn_sched_barrier(0);
    if (st2) asm volatile("s_waitcnt vmcnt(6)" ::: "memory");
    else     asm volatile("s_waitcnt vmcnt(0)" ::: "memory");
    __builtin_amdgcn_s_barrier();
  }

  const int erow = gm0 + wm + fq * 4;
  const int ecol = gn0 + wn + fr;
  #pragma unroll
  for (int m = 0; m < 4; ++m)
    #pragma unroll
    for (int n = 0; n < 4; ++n) {
      size_t base = (size_t)(erow + m * 16) * N + (ecol + n * 16);
      #pragma unroll
      for (int r = 0; r < 4; ++r) {
        float v = acc[m][n][r];
        if constexpr (MODE == 0)
          ((float*)Cv + (size_t)bz * sCz)[base + (size_t)r * N] = v * scale;
        else
          ((_Float16*)Cv + (size_t)bz * sCz)[base + (size_t)r * N] = (_Float16)v;
      }
    }
}

// ---------------------------------------------------------------------------
// Wave-per-row softmax: scores [8192 rows][2048] f16 -> P f16. 4 rows/block.
__global__ __launch_bounds__(256) void softmax_rows(
    const _Float16* __restrict__ S, _Float16* __restrict__ P)
{
  const int w = threadIdx.x >> 6, lane = threadIdx.x & 63;
  const size_t row = (size_t)blockIdx.x * 4 + w;
  const _Float16* sr = S + row * 2048;

  f16x8 v[4];
  #pragma unroll
  for (int c = 0; c < 4; ++c)
    v[c] = *(const f16x8*)(sr + c * 512 + lane * 8);

  float m = -1e30f;
  #pragma unroll
  for (int c = 0; c < 4; ++c)
    #pragma unroll
    for (int j = 0; j < 8; ++j) m = fmaxf(m, (float)v[c][j]);
  #pragma unroll
  for (int o = 32; o >= 1; o >>= 1) m = fmaxf(m, __shfl_xor(m, o));

  float e[4][8];
  float s = 0.f;
  #pragma unroll
  for (int c = 0; c < 4; ++c)
    #pragma unroll
    for (int j = 0; j < 8; ++j) {
      e[c][j] = __expf((float)v[c][j] - m);
      s += e[c][j];
    }
  #pragma unroll
  for (int o = 32; o >= 1; o >>= 1) s += __shfl_xor(s, o);

  const float inv = 1.0f / s;
  _Float16* pr = P + row * 2048;
  #pragma unroll
  for (int c = 0; c < 4; ++c) {
    f16x8 p;
    #pragma unroll
    for (int j = 0; j < 8; ++j) p[j] = (_Float16)(e[c][j] * inv);
    *(f16x8*)(pr + c * 512 + lane * 8) = p;
  }
}

// ---------------------------------------------------------------------------
extern "C" void kernel_launch(void* const* d_in, const int* in_sizes, int n_in,
                              void* d_out, int out_size, void* d_ws, size_t ws_size,
                              hipStream_t stream)
{
  const float* Xk = (const float*)d_in[0];
  const float* Xv = (const float*)d_in[1];
  const float* Xq = (const float*)d_in[2];
  const float* WK = (const float*)d_in[3];
  const float* WV = (const float*)d_in[4];
  const float* WQ = (const float*)d_in[5];
  float* out = (float*)d_out;
  char* ws = (char*)d_ws;

  _Float16* XF   = (_Float16*)(ws);               // 0..48 MiB
  _Float16* WT   = (_Float16*)(ws + 48 * MiB);    // 48..54
  _Float16* PROJ = (_Float16*)(ws + 54 * MiB);    // 54..102 (K,V,Q)
  _Float16* VT   = (_Float16*)(ws + 102 * MiB);   // 102..118
  _Float16* SC   = (_Float16*)(ws + 118 * MiB);   // 118..150 (f16 scores)
  _Float16* P    = (_Float16*)(ws);               // alias XF (dead post-proj)

  _Float16* Kp = PROJ;
  _Float16* Vp = PROJ + MK;
  _Float16* Qp = PROJ + 2 * MK;

  auto* fP  = gemm3b<1>;
  auto* fSC = gemm8p<2>;
  auto* fPV = gemm3b<0>;
  (void)hipFuncSetAttribute((const void*)fP,  hipFuncAttributeMaxDynamicSharedMemorySize, 147456);
  (void)hipFuncSetAttribute((const void*)fSC, hipFuncAttributeMaxDynamicSharedMemorySize, 131072);
  (void)hipFuncSetAttribute((const void*)fPV, hipFuncAttributeMaxDynamicSharedMemorySize, 147456);

  // 1) X -> f16 (k,v,q)
  convert_x<<<dim3(8192, 1, 3), 256, 0, stream>>>(Xk, Xv, Xq, XF);
  // 2) W -> W^T f16 (K,V,Q)
  transpose_conv_w<<<dim3(32, 32, 3), 256, 0, stream>>>(WK, WV, WQ, WT);
  // 3) projections: PROJ[z] = XF[z] @ WT[z]^T  (M=8192,N=1024,K=1024)
  //    grid 8x32x3 = 768 blocks = 3.0 rounds
  gemm3b<1><<<dim3(8, 32, 3), 512, 147456, stream>>>(
      XF, MK, WT, WSZ, PROJ, MK, 1024, 1024, 1.0f);
  // 4) V^T per batch
  transpose_v<<<dim3(32, 64, 4), 256, 0, stream>>>(Vp, VT);
  // 5) scores[b] = Q[b]@K[b]^T / sqrt(2048) -> f16  (grid 256 = 1 round)
  gemm8p<2><<<dim3(8, 8, 4), 512, 131072, stream>>>(
      Qp, (size_t)2048 * 1024, Kp, (size_t)2048 * 1024,
      SC, (size_t)2048 * 2048, 2048, 1024, 0.022097086912079608f);
  // 6) softmax (wave-per-row) -> P f16
  softmax_rows<<<dim3(2048), 256, 0, stream>>>(SC, P);
  // 7) out[b] = P[b] @ VT[b]^T  (M=2048,N=1024,K=2048; grid 256 = 1 round)
  gemm3b<0><<<dim3(8, 8, 4), 512, 147456, stream>>>(
      P, (size_t)2048 * 2048, VT, (size_t)1024 * 2048,
      out, (size_t)2048 * 1024, 1024, 2048, 1.0f);
}

// Round 10
// 194.073 us; speedup vs baseline: 1.0374x; 1.0374x over previous
//
#include <hip/hip_runtime.h>
#include <hip/hip_bf16.h>

// ---------------------------------------------------------------------------
// AttentionHead B=4,S=2048,D=1024 — all-f16 pipeline, round 10.
// gemmv (new): 256x256 BK=64, cluster-prefetch schedule — ds_reads of MFMA
//   cluster c issued during cluster c-1's MFMAs, counted lgkmcnt(4/8/0),
//   only 2 barriers/K-tile. Theory: r7-r9's per-phase {reads;barrier;lgkm(0);
//   MFMA;barrier} lockstep ADDS read-delivery (~750cyc) to MFMA (~614cyc)
//   -> 39% util. Overlap -> ~990 cyc/tile -> ~60%.
// gemm3b (r9): PV. softmax/converts unchanged.
// ws (MiB): XF@0(48) WT@48(6) PROJ@54(48) VT@102(16) SC@118(32,f16)
//           P@0(32,f16, alias XF). high-water 150 MiB.
// ---------------------------------------------------------------------------

typedef __attribute__((ext_vector_type(4))) float    f32x4;
typedef __attribute__((ext_vector_type(8))) _Float16 f16x8;
typedef __attribute__((ext_vector_type(4))) _Float16 f16x4;

constexpr size_t MiB = 1u << 20;
constexpr size_t MK  = (size_t)8192 * 1024;
constexpr size_t WSZ = (size_t)1024 * 1024;

__device__ __forceinline__ void gload_lds16(const void* g, void* l) {
  __builtin_amdgcn_global_load_lds(
      (const __attribute__((address_space(1))) unsigned int*)g,
      (__attribute__((address_space(3))) unsigned int*)l, 16, 0, 0);
}

#define MFMA16(a, b, c) __builtin_amdgcn_mfma_f32_16x16x32_f16(a, b, c, 0, 0, 0)

// XCD-chunked bijective block swizzle (requires total blocks % 8 == 0).
__device__ __forceinline__ void swz_block(int& bx, int& by, int& bz) {
  unsigned gx = gridDim.x, gy = gridDim.y;
  unsigned flat = blockIdx.x + gx * (blockIdx.y + gy * blockIdx.z);
  unsigned total = gx * gy * gridDim.z;
  unsigned cpx = total >> 3;
  unsigned s = (flat & 7) * cpx + (flat >> 3);
  bx = s % gx; s /= gx; by = s % gy; bz = s / gy;
}

// ---------------------------------------------------------------------------
__global__ __launch_bounds__(256) void convert_x(
    const float* __restrict__ x0, const float* __restrict__ x1,
    const float* __restrict__ x2, _Float16* __restrict__ XF)
{
  const int z = blockIdx.z;
  const float* x = z == 0 ? x0 : (z == 1 ? x1 : x2);
  size_t i = ((size_t)blockIdx.x * 256 + threadIdx.x) * 4;
  float4 v = *(const float4*)(x + i);
  f16x4 h = {(_Float16)v.x, (_Float16)v.y, (_Float16)v.z, (_Float16)v.w};
  *(f16x4*)(XF + (size_t)z * MK + i) = h;
}

// ---------------------------------------------------------------------------
__global__ __launch_bounds__(256) void transpose_conv_w(
    const float* __restrict__ w0, const float* __restrict__ w1,
    const float* __restrict__ w2, _Float16* __restrict__ WT)
{
  const int z = blockIdx.z;
  const float* W = z == 0 ? w0 : (z == 1 ? w1 : w2);
  _Float16* o = WT + (size_t)z * WSZ;
  __shared__ float tile[32][33];
  const int bx = blockIdx.x * 32;
  const int by = blockIdx.y * 32;
  const int tx = threadIdx.x & 31, ty = threadIdx.x >> 5;
  #pragma unroll
  for (int r = 0; r < 32; r += 8)
    tile[ty + r][tx] = W[(size_t)(by + ty + r) * 1024 + bx + tx];
  __syncthreads();
  #pragma unroll
  for (int r = 0; r < 32; r += 8)
    o[(size_t)(bx + ty + r) * 1024 + by + tx] = (_Float16)tile[tx][ty + r];
}

// ---------------------------------------------------------------------------
__global__ __launch_bounds__(256) void transpose_v(
    const _Float16* __restrict__ V, _Float16* __restrict__ Vt)
{
  const _Float16* v = V + (size_t)blockIdx.z * 2048 * 1024;
  _Float16* o = Vt + (size_t)blockIdx.z * 1024 * 2048;
  __shared__ _Float16 tile[32][33];
  const int bx = blockIdx.x * 32;   // e
  const int by = blockIdx.y * 32;   // s
  const int tx = threadIdx.x & 31, ty = threadIdx.x >> 5;
  #pragma unroll
  for (int r = 0; r < 32; r += 8)
    tile[ty + r][tx] = v[(size_t)(by + ty + r) * 1024 + bx + tx];
  __syncthreads();
  #pragma unroll
  for (int r = 0; r < 32; r += 8)
    o[(size_t)(bx + ty + r) * 2048 + by + tx] = tile[tx][ty + r];
}

// ---------------------------------------------------------------------------
// gemmv: 256x256, BK=64, 8 waves (2Mx4N, wave 128x64), 2x64KiB LDS dbuf.
// Cluster-prefetch: reads for cluster c issued before cluster c-1's MFMAs,
// counted lgkmcnt; 2 barriers/tile (pre-C3 + boundary); boundary vmcnt(2).
// MODE 0: f32*scale ; 1: f16 ; 2: f16*scale.
template <int MODE>
__global__ __launch_bounds__(512, 2) void gemmv(
    const _Float16* __restrict__ At, size_t sA,
    const _Float16* __restrict__ Bt, size_t sB,
    void* __restrict__ Cv, size_t sCz,
    int N, int K, float scale)
{
  extern __shared__ char lds[];
  int bx, by, bz;
  swz_block(bx, by, bz);
  const _Float16* A = At + (size_t)bz * sA;
  const _Float16* B = Bt + (size_t)bz * sB;

  const int gm0 = by * 256, gn0 = bx * 256;
  const int tid = threadIdx.x;
  const int lane = tid & 63, wave = tid >> 6;
  const int wm = (wave >> 2) * 128;
  const int wn = (wave & 3) * 64;
  const int fr = lane & 15, fq = lane >> 4;
  const int nkt = K >> 6;

  const int clog = ((tid & 7) ^ ((tid >> 3) & 7)) * 8;
  const _Float16* srcA = A + (size_t)(gm0 + (tid >> 3)) * K + clog;
  const _Float16* srcB = B + (size_t)(gn0 + (tid >> 3)) * K + clog;
  char* const dst0 = lds + tid * 16;

  // half-tiles: h0 = A rows 0-127, h1 = A rows 128-255, h2 = B 0-127, h3 = B 128-255
  auto SH = [&](int tile, int h) {
    const _Float16* s = (h < 2 ? srcA : srcB) + (size_t)((h & 1) * 128) * K
                        + tile * 64;
    char* d = dst0 + (tile & 1) * 65536 + h * 16384;
    gload_lds16(s, d);
    gload_lds16(s + (size_t)64 * K, d + 8192);
  };

  const int axor = fr & 7;
  const int pc0 = (fq ^ axor) * 16;
  const int pc1 = ((4 + fq) ^ axor) * 16;
  const int arb = (wm + fr) * 128;
  const int brb = 32768 + (wn + fr) * 128;

  f32x4 acc[8][4] = {};
  f16x8 afl[4][2], afh[4][2], b0[2][2], b1[2][2];

  // prologue: tile 0 fully + h0 of tile 1
  SH(0, 0); SH(0, 1); SH(0, 2); SH(0, 3);
  if (nkt > 1) {
    SH(1, 0);
    asm volatile("s_waitcnt vmcnt(2)" ::: "memory");
  } else {
    asm volatile("s_waitcnt vmcnt(0)" ::: "memory");
  }
  __builtin_amdgcn_s_barrier();
  __builtin_amdgcn_sched_barrier(0);

  // initial C0 reads (tile 0): afl(8) + b0(4)
  {
    const char* buf = lds;
    #pragma unroll
    for (int mi = 0; mi < 4; ++mi) {
      afl[mi][0] = *(const f16x8*)(buf + arb + mi * 2048 + pc0);
      afl[mi][1] = *(const f16x8*)(buf + arb + mi * 2048 + pc1);
    }
    #pragma unroll
    for (int ni = 0; ni < 2; ++ni) {
      b0[ni][0] = *(const f16x8*)(buf + brb + ni * 2048 + pc0);
      b0[ni][1] = *(const f16x8*)(buf + brb + ni * 2048 + pc1);
    }
  }

  for (int t = 0; t < nkt; ++t) {
    const char* buf  = lds + (t & 1) * 65536;
    const char* nbuf = lds + ((t + 1) & 1) * 65536;
    const bool st1 = (t + 1) < nkt;
    const bool st2 = (t + 2) < nkt;

    // ---- C0: prefetch b1(4); stage h1(t+1); wait afl+b0; MFMA m0-3 x n0-1
    #pragma unroll
    for (int ni = 0; ni < 2; ++ni) {
      b1[ni][0] = *(const f16x8*)(buf + brb + (ni + 2) * 2048 + pc0);
      b1[ni][1] = *(const f16x8*)(buf + brb + (ni + 2) * 2048 + pc1);
    }
    if (st1) SH(t + 1, 1);
    asm volatile("s_waitcnt lgkmcnt(4)" ::: "memory");
    __builtin_amdgcn_sched_barrier(0);
    __builtin_amdgcn_s_setprio(1);
    #pragma unroll
    for (int mi = 0; mi < 4; ++mi)
      #pragma unroll
      for (int ni = 0; ni < 2; ++ni)
        #pragma unroll
        for (int kk = 0; kk < 2; ++kk)
          acc[mi][ni] = MFMA16(afl[mi][kk], b0[ni][kk], acc[mi][ni]);
    __builtin_amdgcn_s_setprio(0);
    __builtin_amdgcn_sched_barrier(0);

    // ---- C1: prefetch afh(8); stage h2(t+1); wait b1; MFMA m0-3 x n2-3
    #pragma unroll
    for (int mi = 0; mi < 4; ++mi) {
      afh[mi][0] = *(const f16x8*)(buf + arb + (mi + 4) * 2048 + pc0);
      afh[mi][1] = *(const f16x8*)(buf + arb + (mi + 4) * 2048 + pc1);
    }
    if (st1) SH(t + 1, 2);
    asm volatile("s_waitcnt lgkmcnt(8)" ::: "memory");
    __builtin_amdgcn_sched_barrier(0);
    __builtin_amdgcn_s_setprio(1);
    #pragma unroll
    for (int mi = 0; mi < 4; ++mi)
      #pragma unroll
      for (int ni = 0; ni < 2; ++ni)
        #pragma unroll
        for (int kk = 0; kk < 2; ++kk)
          acc[mi][ni + 2] = MFMA16(afl[mi][kk], b1[ni][kk], acc[mi][ni + 2]);
    __builtin_amdgcn_s_setprio(0);
    __builtin_amdgcn_sched_barrier(0);

    // ---- C2: stage h3(t+1); wait afh; MFMA m4-7 x n0-1
    if (st1) SH(t + 1, 3);
    asm volatile("s_waitcnt lgkmcnt(0)" ::: "memory");
    __builtin_amdgcn_sched_barrier(0);
    __builtin_amdgcn_s_setprio(1);
    #pragma unroll
    for (int mi = 0; mi < 4; ++mi)
      #pragma unroll
      for (int ni = 0; ni < 2; ++ni)
        #pragma unroll
        for (int kk = 0; kk < 2; ++kk)
          acc[mi + 4][ni] = MFMA16(afh[mi][kk], b0[ni][kk], acc[mi + 4][ni]);
    __builtin_amdgcn_s_setprio(0);
    __builtin_amdgcn_sched_barrier(0);
    __builtin_amdgcn_s_barrier();   // all waves done reading buf A0 (pre-h0 write)

    // ---- C3: stage h0(t+2) (writes buf A0 region); MFMA m4-7 x n2-3
    if (st2) SH(t + 2, 0);
    __builtin_amdgcn_s_setprio(1);
    #pragma unroll
    for (int mi = 0; mi < 4; ++mi)
      #pragma unroll
      for (int ni = 0; ni < 2; ++ni)
        #pragma unroll
        for (int kk = 0; kk < 2; ++kk)
          acc[mi + 4][ni + 2] = MFMA16(afh[mi][kk], b1[ni][kk], acc[mi + 4][ni + 2]);
    __builtin_amdgcn_s_setprio(0);
    __builtin_amdgcn_sched_barrier(0);

    // ---- boundary: t+1's halves h0..h3 landed; h0(t+2) may stay in flight
    if (st2) asm volatile("s_waitcnt vmcnt(2)" ::: "memory");
    else     asm volatile("s_waitcnt vmcnt(0)" ::: "memory");
    __builtin_amdgcn_s_barrier();
    __builtin_amdgcn_sched_barrier(0);

    // ---- issue next tile's C0 reads (afl + b0 from nbuf)
    if (st1) {
      #pragma unroll
      for (int mi = 0; mi < 4; ++mi) {
        afl[mi][0] = *(const f16x8*)(nbuf + arb + mi * 2048 + pc0);
        afl[mi][1] = *(const f16x8*)(nbuf + arb + mi * 2048 + pc1);
      }
      #pragma unroll
      for (int ni = 0; ni < 2; ++ni) {
        b0[ni][0] = *(const f16x8*)(nbuf + brb + ni * 2048 + pc0);
        b0[ni][1] = *(const f16x8*)(nbuf + brb + ni * 2048 + pc1);
      }
    }
  }

  // ---- epilogue: C/D layout col=fr, row=fq*4+r
  const int erow = gm0 + wm + fq * 4;
  const int ecol = gn0 + wn + fr;
  #pragma unroll
  for (int m = 0; m < 8; ++m)
    #pragma unroll
    for (int n = 0; n < 4; ++n) {
      size_t base = (size_t)(erow + m * 16) * N + (ecol + n * 16);
      #pragma unroll
      for (int r = 0; r < 4; ++r) {
        float v = acc[m][n][r];
        if constexpr (MODE == 0)
          ((float*)Cv + (size_t)bz * sCz)[base + (size_t)r * N] = v * scale;
        else if constexpr (MODE == 1)
          ((_Float16*)Cv + (size_t)bz * sCz)[base + (size_t)r * N] = (_Float16)v;
        else
          ((_Float16*)Cv + (size_t)bz * sCz)[base + (size_t)r * N] =
              (_Float16)(v * scale);
      }
    }
}

// ---------------------------------------------------------------------------
// gemm3b (r9, proven): 256x128 BK=64 triple-buffered. For PV.
// MODE 0: f32*scale ; 1: f16.
template <int MODE>
__global__ __launch_bounds__(512, 2) void gemm3b(
    const _Float16* __restrict__ At, size_t sA,
    const _Float16* __restrict__ Bt, size_t sB,
    void* __restrict__ Cv, size_t sCz,
    int N, int K, float scale)
{
  extern __shared__ char lds[];
  int bx, by, bz;
  swz_block(bx, by, bz);
  const _Float16* A = At + (size_t)bz * sA;
  const _Float16* B = Bt + (size_t)bz * sB;

  const int gm0 = by * 256, gn0 = bx * 128;
  const int tid = threadIdx.x;
  const int lane = tid & 63, wave = tid >> 6;
  const int wm = (wave >> 1) * 64;
  const int wn = (wave & 1) * 64;
  const int fr = lane & 15, fq = lane >> 4;
  const int nkt = K >> 6;

  const int clog = ((tid & 7) ^ ((tid >> 3) & 7)) * 8;
  const _Float16* srcA = A + (size_t)(gm0 + (tid >> 3)) * K + clog;
  const _Float16* srcB = B + (size_t)(gn0 + (tid >> 3)) * K + clog;
  char* const dst0 = lds + tid * 16;

  auto SHU = [&](int tile, int u) {
    const _Float16* s = (u < 4 ? srcA + (size_t)(u * 64) * K
                               : srcB + (size_t)((u - 4) * 64) * K)
                        + tile * 64;
    gload_lds16(s, dst0 + (tile % 3) * 49152 + u * 8192);
  };

  const int axor = fr & 7;
  const int pc0 = (fq ^ axor) * 16;
  const int pc1 = ((4 + fq) ^ axor) * 16;
  const int arb = (wm + fr) * 128;
  const int brb = 32768 + (wn + fr) * 128;

  f32x4 acc[4][4] = {};
  f16x8 af[4][2], b0[2][2], b1[2][2];

  #pragma unroll
  for (int u = 0; u < 6; ++u) SHU(0, u);
  if (nkt > 1) {
    #pragma unroll
    for (int u = 0; u < 6; ++u) SHU(1, u);
    asm volatile("s_waitcnt vmcnt(6)" ::: "memory");
  } else {
    asm volatile("s_waitcnt vmcnt(0)" ::: "memory");
  }
  __builtin_amdgcn_s_barrier();
  __builtin_amdgcn_sched_barrier(0);

  for (int t = 0; t < nkt; ++t) {
    const char* buf = lds + (t % 3) * 49152;
    const bool st2 = (t + 2) < nkt;

    #pragma unroll
    for (int mi = 0; mi < 4; ++mi) {
      af[mi][0] = *(const f16x8*)(buf + arb + mi * 2048 + pc0);
      af[mi][1] = *(const f16x8*)(buf + arb + mi * 2048 + pc1);
    }
    #pragma unroll
    for (int ni = 0; ni < 2; ++ni) {
      b0[ni][0] = *(const f16x8*)(buf + brb + ni * 2048 + pc0);
      b0[ni][1] = *(const f16x8*)(buf + brb + ni * 2048 + pc1);
    }
    if (st2) { SHU(t + 2, 0); SHU(t + 2, 1); SHU(t + 2, 2); }
    __builtin_amdgcn_s_barrier();
    asm volatile("s_waitcnt lgkmcnt(0)" ::: "memory");
    __builtin_amdgcn_sched_barrier(0);
    __builtin_amdgcn_s_setprio(1);
    #pragma unroll
    for (int mi = 0; mi < 4; ++mi)
      #pragma unroll
      for (int ni = 0; ni < 2; ++ni)
        #pragma unroll
        for (int kk = 0; kk < 2; ++kk)
          acc[mi][ni] = MFMA16(af[mi][kk], b0[ni][kk], acc[mi][ni]);
    __builtin_amdgcn_s_setprio(0);
    __builtin_amdgcn_sched_barrier(0);
    __builtin_amdgcn_s_barrier();

    #pragma unroll
    for (int ni = 0; ni < 2; ++ni) {
      b1[ni][0] = *(const f16x8*)(buf + brb + (ni + 2) * 2048 + pc0);
      b1[ni][1] = *(const f16x8*)(buf + brb + (ni + 2) * 2048 + pc1);
    }
    if (st2) { SHU(t + 2, 3); SHU(t + 2, 4); SHU(t + 2, 5); }
    __builtin_amdgcn_s_barrier();
    asm volatile("s_waitcnt lgkmcnt(0)" ::: "memory");
    __builtin_amdgcn_sched_barrier(0);
    __builtin_amdgcn_s_setprio(1);
    #pragma unroll
    for (int mi = 0; mi < 4; ++mi)
      #pragma unroll
      for (int ni = 0; ni < 2; ++ni)
        #pragma unroll
        for (int kk = 0; kk < 2; ++kk)
          acc[mi][ni + 2] = MFMA16(af[mi][kk], b1[ni][kk], acc[mi][ni + 2]);
    __builtin_amdgcn_s_setprio(0);
    __builtin_amdgcn_sched_barrier(0);
    if (st2) asm volatile("s_waitcnt vmcnt(6)" ::: "memory");
    else     asm volatile("s_waitcnt vmcnt(0)" ::: "memory");
    __builtin_amdgcn_s_barrier();
  }

  const int erow = gm0 + wm + fq * 4;
  const int ecol = gn0 + wn + fr;
  #pragma unroll
  for (int m = 0; m < 4; ++m)
    #pragma unroll
    for (int n = 0; n < 4; ++n) {
      size_t base = (size_t)(erow + m * 16) * N + (ecol + n * 16);
      #pragma unroll
      for (int r = 0; r < 4; ++r) {
        float v = acc[m][n][r];
        if constexpr (MODE == 0)
          ((float*)Cv + (size_t)bz * sCz)[base + (size_t)r * N] = v * scale;
        else
          ((_Float16*)Cv + (size_t)bz * sCz)[base + (size_t)r * N] = (_Float16)v;
      }
    }
}

// ---------------------------------------------------------------------------
// Wave-per-row softmax: scores [8192 rows][2048] f16 -> P f16. 4 rows/block.
__global__ __launch_bounds__(256) void softmax_rows(
    const _Float16* __restrict__ S, _Float16* __restrict__ P)
{
  const int w = threadIdx.x >> 6, lane = threadIdx.x & 63;
  const size_t row = (size_t)blockIdx.x * 4 + w;
  const _Float16* sr = S + row * 2048;

  f16x8 v[4];
  #pragma unroll
  for (int c = 0; c < 4; ++c)
    v[c] = *(const f16x8*)(sr + c * 512 + lane * 8);

  float m = -1e30f;
  #pragma unroll
  for (int c = 0; c < 4; ++c)
    #pragma unroll
    for (int j = 0; j < 8; ++j) m = fmaxf(m, (float)v[c][j]);
  #pragma unroll
  for (int o = 32; o >= 1; o >>= 1) m = fmaxf(m, __shfl_xor(m, o));

  float e[4][8];
  float s = 0.f;
  #pragma unroll
  for (int c = 0; c < 4; ++c)
    #pragma unroll
    for (int j = 0; j < 8; ++j) {
      e[c][j] = __expf((float)v[c][j] - m);
      s += e[c][j];
    }
  #pragma unroll
  for (int o = 32; o >= 1; o >>= 1) s += __shfl_xor(s, o);

  const float inv = 1.0f / s;
  _Float16* pr = P + row * 2048;
  #pragma unroll
  for (int c = 0; c < 4; ++c) {
    f16x8 p;
    #pragma unroll
    for (int j = 0; j < 8; ++j) p[j] = (_Float16)(e[c][j] * inv);
    *(f16x8*)(pr + c * 512 + lane * 8) = p;
  }
}

// ---------------------------------------------------------------------------
extern "C" void kernel_launch(void* const* d_in, const int* in_sizes, int n_in,
                              void* d_out, int out_size, void* d_ws, size_t ws_size,
                              hipStream_t stream)
{
  const float* Xk = (const float*)d_in[0];
  const float* Xv = (const float*)d_in[1];
  const float* Xq = (const float*)d_in[2];
  const float* WK = (const float*)d_in[3];
  const float* WV = (const float*)d_in[4];
  const float* WQ = (const float*)d_in[5];
  float* out = (float*)d_out;
  char* ws = (char*)d_ws;

  _Float16* XF   = (_Float16*)(ws);               // 0..48 MiB
  _Float16* WT   = (_Float16*)(ws + 48 * MiB);    // 48..54
  _Float16* PROJ = (_Float16*)(ws + 54 * MiB);    // 54..102 (K,V,Q)
  _Float16* VT   = (_Float16*)(ws + 102 * MiB);   // 102..118
  _Float16* SC   = (_Float16*)(ws + 118 * MiB);   // 118..150 (f16 scores)
  _Float16* P    = (_Float16*)(ws);               // alias XF (dead post-proj)

  _Float16* Kp = PROJ;
  _Float16* Vp = PROJ + MK;
  _Float16* Qp = PROJ + 2 * MK;

  auto* fP  = gemmv<1>;
  auto* fSC = gemmv<2>;
  auto* fPV = gemm3b<0>;
  (void)hipFuncSetAttribute((const void*)fP,  hipFuncAttributeMaxDynamicSharedMemorySize, 131072);
  (void)hipFuncSetAttribute((const void*)fSC, hipFuncAttributeMaxDynamicSharedMemorySize, 131072);
  (void)hipFuncSetAttribute((const void*)fPV, hipFuncAttributeMaxDynamicSharedMemorySize, 147456);

  // 1) X -> f16 (k,v,q)
  convert_x<<<dim3(8192, 1, 3), 256, 0, stream>>>(Xk, Xv, Xq, XF);
  // 2) W -> W^T f16 (K,V,Q)
  transpose_conv_w<<<dim3(32, 32, 3), 256, 0, stream>>>(WK, WV, WQ, WT);
  // 3) projections: PROJ[z] = XF[z] @ WT[z]^T  (M=8192,N=1024,K=1024)
  gemmv<1><<<dim3(4, 32, 3), 512, 131072, stream>>>(
      XF, MK, WT, WSZ, PROJ, MK, 1024, 1024, 1.0f);
  // 4) V^T per batch
  transpose_v<<<dim3(32, 64, 4), 256, 0, stream>>>(Vp, VT);
  // 5) scores[b] = Q[b]@K[b]^T / sqrt(2048) -> f16  (grid 256 = 1 round)
  gemmv<2><<<dim3(8, 8, 4), 512, 131072, stream>>>(
      Qp, (size_t)2048 * 1024, Kp, (size_t)2048 * 1024,
      SC, (size_t)2048 * 2048, 2048, 1024, 0.022097086912079608f);
  // 6) softmax (wave-per-row) -> P f16
  softmax_rows<<<dim3(2048), 256, 0, stream>>>(SC, P);
  // 7) out[b] = P[b] @ VT[b]^T  (M=2048,N=1024,K=2048; grid 256 = 1 round)
  gemm3b<0><<<dim3(8, 8, 4), 512, 147456, stream>>>(
      P, (size_t)2048 * 2048, VT, (size_t)1024 * 2048,
      out, (size_t)2048 * 1024, 1024, 2048, 1.0f);
}